// Round 8
// baseline (844.005 us; speedup 1.0000x reference)
//
#include <hip/hip_runtime.h>
#include <hip/hip_bf16.h>

typedef __bf16 bf16_t;
typedef __attribute__((ext_vector_type(8))) __bf16 bf16x8;
typedef __attribute__((ext_vector_type(4))) float f32x4;
typedef __attribute__((ext_vector_type(4))) unsigned int u32x4;

// ---------------------------------------------------------------------------
__device__ __forceinline__ void gload_lds16(const bf16_t* g, bf16_t* l) {
    __builtin_amdgcn_global_load_lds(
        (const __attribute__((address_space(1))) void*)g,
        (__attribute__((address_space(3))) void*)l,
        16, 0, 0);
}

__device__ __forceinline__ float gelu_f(float v) {
    float u = 0.7978845608028654f * (v + 0.044715f * v * v * v);
    float e = __expf(-2.f * u);
    float t = __fdividef(1.f - e, 1.f + e);   // tanh(u)
    return 0.5f * v * (1.f + t);
}

// ---------------------------------------------------------------------------
// MXFP4 quantize: one (32-block b, column n) -> 32 dequantized bf16 written
// transposed. Exact: pow2 scale, E2M1 midpoint rounding, bf16-exact values.
__device__ __forceinline__ void quant_one(const float* __restrict__ w,
                                          bf16_t* __restrict__ wt,
                                          int K, int N, int tix) {
    int n = tix % N;
    int b = tix / N;
    const float* src = w + (size_t)b * 32 * N + n;
    float v[32];
    float amax = 0.f;
#pragma unroll
    for (int i = 0; i < 32; ++i) {
        v[i] = __builtin_nontemporal_load(src + (size_t)i * N);
        amax = fmaxf(amax, fabsf(v[i]));
    }
    unsigned eb = (__float_as_uint(amax) >> 23) & 0xFF;
    float scale = __uint_as_float((eb - 2u) << 23);        // 2^(E-2)
    float inv   = __uint_as_float((256u - eb) << 23);      // 2^-(E-2)
    if (amax == 0.f) { scale = 0.f; inv = 0.f; }
    bf16_t dq[32];
#pragma unroll
    for (int i = 0; i < 32; ++i) {
        float x  = v[i] * inv;
        float ax = fabsf(x);
        float q = ax < 0.25f ? 0.0f : ax < 0.75f ? 0.5f : ax < 1.25f ? 1.0f :
                  ax < 1.75f ? 1.5f : ax < 2.5f  ? 2.0f : ax < 3.5f  ? 3.0f :
                  ax < 5.0f  ? 4.0f : 6.0f;
        float d = copysignf(q * scale, x);
        dq[i] = (bf16_t)d;
    }
    bf16_t* dst = wt + (size_t)n * K + b * 32;
#pragma unroll
    for (int j = 0; j < 4; ++j) {
        bf16x8 p;
#pragma unroll
        for (int t = 0; t < 8; ++t) p[t] = dq[j * 8 + t];
        *(bf16x8*)(dst + j * 8) = p;
    }
}

// ---------------------------------------------------------------------------
// Fused prep: blocks [0, cvtBlocks) convert inputs->bf16 (8 elems/thread);
// blocks [cvtBlocks, ...) quantize up-weights.
__global__ void prep_kernel(const float* __restrict__ in, bf16_t* __restrict__ out,
                            int ncvt, int cvtBlocks,
                            const float* __restrict__ upw, bf16_t* __restrict__ upwt,
                            int K, int N) {
    int bid = blockIdx.x;
    if (bid < cvtBlocks) {
        int i = (bid * blockDim.x + threadIdx.x) << 3;
        if (i >= ncvt) return;
        const f32x4* p = (const f32x4*)(in + i);
        f32x4 a = __builtin_nontemporal_load(p);
        f32x4 b = __builtin_nontemporal_load(p + 1);
        bf16x8 o;
        o[0] = (bf16_t)a[0]; o[1] = (bf16_t)a[1]; o[2] = (bf16_t)a[2]; o[3] = (bf16_t)a[3];
        o[4] = (bf16_t)b[0]; o[5] = (bf16_t)b[1]; o[6] = (bf16_t)b[2]; o[7] = (bf16_t)b[3];
        *(bf16x8*)(out + i) = o;
    } else {
        int tix = (bid - cvtBlocks) * blockDim.x + threadIdx.x;
        if (tix >= (K >> 5) * N) return;
        quant_one(upw, upwt, K, N, tix);
    }
}

// standalone down-weight quantize (reverted from GEMM1 fusion: that cost 46us)
__global__ void quantize_kernel(const float* __restrict__ w, bf16_t* __restrict__ wt,
                                int K, int N) {
    int tix = blockIdx.x * blockDim.x + threadIdx.x;
    if (tix >= (K >> 5) * N) return;
    quant_one(w, wt, K, N, tix);
}

// ---------------------------------------------------------------------------
// 256x256x(BK=64) 8-phase bf16 GEMM (T1+T2+T3+T4+T5).
// PROBE=1: staging addresses pinned to kt=0 (L2-hot after iter 1), epilogue to
// a fixed 128KB scratch tile. Identical instruction/barrier/vmcnt structure --
// isolates data-path latency (probe fast) vs round structure (probe ~= real).
#define VMW4  asm volatile("s_waitcnt vmcnt(4)" ::: "memory")
#define VMW0  asm volatile("s_waitcnt vmcnt(0)" ::: "memory")
#define BARR  asm volatile("s_barrier" ::: "memory")
#define LGKM0 asm volatile("s_waitcnt lgkmcnt(0)" ::: "memory")

#define MFMA_ROW(MI, A0, A1)                                                          \
    acc[MI][0] = __builtin_amdgcn_mfma_f32_16x16x32_bf16(A0, bf00, acc[MI][0],0,0,0); \
    acc[MI][0] = __builtin_amdgcn_mfma_f32_16x16x32_bf16(A1, bf01, acc[MI][0],0,0,0); \
    acc[MI][1] = __builtin_amdgcn_mfma_f32_16x16x32_bf16(A0, bf10, acc[MI][1],0,0,0); \
    acc[MI][1] = __builtin_amdgcn_mfma_f32_16x16x32_bf16(A1, bf11, acc[MI][1],0,0,0); \
    acc[MI][2] = __builtin_amdgcn_mfma_f32_16x16x32_bf16(A0, bf20, acc[MI][2],0,0,0); \
    acc[MI][2] = __builtin_amdgcn_mfma_f32_16x16x32_bf16(A1, bf21, acc[MI][2],0,0,0); \
    acc[MI][3] = __builtin_amdgcn_mfma_f32_16x16x32_bf16(A0, bf30, acc[MI][3],0,0,0); \
    acc[MI][3] = __builtin_amdgcn_mfma_f32_16x16x32_bf16(A1, bf31, acc[MI][3],0,0,0);

#define PHASE(BUF, P, STAGE_STMT, TAIL_STMT)                                          \
  {                                                                                   \
    af00 = lda(BUF, 2*(P),   0); af01 = lda(BUF, 2*(P),   1);                         \
    af10 = lda(BUF, 2*(P)+1, 0); af11 = lda(BUF, 2*(P)+1, 1);                         \
    if ((P) == 0) {                                                                   \
      bf00 = ldb(BUF,0,0); bf01 = ldb(BUF,0,1);                                       \
      bf10 = ldb(BUF,1,0); bf11 = ldb(BUF,1,1);                                       \
      bf20 = ldb(BUF,2,0); bf21 = ldb(BUF,2,1);                                       \
      bf30 = ldb(BUF,3,0); bf31 = ldb(BUF,3,1);                                       \
    }                                                                                 \
    STAGE_STMT;                                                                       \
    BARR;                                                                             \
    LGKM0;                                                                            \
    __builtin_amdgcn_s_setprio(1);                                                    \
    MFMA_ROW(2*(P),   af00, af01);                                                    \
    MFMA_ROW(2*(P)+1, af10, af11);                                                    \
    __builtin_amdgcn_s_setprio(0);                                                    \
    TAIL_STMT;                                                                        \
    BARR;                                                                             \
  }

template <int EPI, int MAP, int PROBE>
__device__ __forceinline__ void gemm_body(
        const bf16_t* __restrict__ A, const bf16_t* __restrict__ Bt,
        const float* __restrict__ bias, void* __restrict__ Cout,
        int M, int N, int K, char* smem) {
    bf16_t* sAp = (bf16_t*)smem;               // [2][256*64]
    bf16_t* sBp = (bf16_t*)(smem + 65536);     // [2][256*64]
    const int tid     = threadIdx.x;
    const int lane    = tid & 63;
    const int wv      = tid >> 6;
    const int wr      = wv >> 2;
    const int wc      = wv & 3;
    const int laneLow = lane & 15;
    const int laneHi  = lane >> 4;

    int bm, bn;
    const int bid = blockIdx.x;
    if (MAP == 1) {
        const int xcd = bid & 7;
        const int l   = bid >> 3;
        const int r   = l >> 5;
        const int u   = l & 31;
        bm = r * 8 + ((xcd >> 2) << 2) + (u >> 3);
        bn = ((xcd & 3) << 3) + (u & 7);
    } else {
        const int ntn = N >> 8;
        const int nwg = gridDim.x;
        int wg  = (bid & 7) * (nwg >> 3) + (bid >> 3);
        bm = wg / ntn; bn = wg % ntn;
    }

    const int sr8 = lane >> 3;
    const int swz = (((lane & 7) ^ sr8) << 3);
    const bf16_t* aSrc = A  + (size_t)(bm * 256 + wv * 8 + sr8) * K + swz;
    const bf16_t* bSrc = Bt + (size_t)(bn * 256 + wv * 8 + sr8) * K + swz;

    auto stageA = [&](int b, int kt, int h) {
        const int k2 = PROBE ? 0 : kt;
        const bf16_t* s = aSrc + (size_t)(h * 128) * K + k2 * 64;
        gload_lds16(s,                &sAp[b * 16384 + (h * 128 + wv * 8) * 64]);
        gload_lds16(s + (size_t)64*K, &sAp[b * 16384 + (h * 128 + 64 + wv * 8) * 64]);
    };
    auto stageB = [&](int b, int kt, int h) {
        const int k2 = PROBE ? 0 : kt;
        const bf16_t* s = bSrc + (size_t)(h * 128) * K + k2 * 64;
        gload_lds16(s,                &sBp[b * 16384 + (h * 128 + wv * 8) * 64]);
        gload_lds16(s + (size_t)64*K, &sBp[b * 16384 + (h * 128 + 64 + wv * 8) * 64]);
    };

    const int s7  = laneLow & 7;
    const int xk0 = ((laneHi) ^ s7) << 3;
    const int xk1 = ((4 + laneHi) ^ s7) << 3;
    const int aOffBase = (wr * 128 + laneLow) * 64;
    const int bOffBase = (wc * 64 + laneLow) * 64;
    auto lda = [&](int b, int m, int ks) -> bf16x8 {
        return *(const bf16x8*)(&sAp[b * 16384 + aOffBase + m * 1024 + (ks ? xk1 : xk0)]);
    };
    auto ldb = [&](int b, int n2, int ks) -> bf16x8 {
        return *(const bf16x8*)(&sBp[b * 16384 + bOffBase + n2 * 1024 + (ks ? xk1 : xk0)]);
    };

    f32x4 acc[8][4];
#pragma unroll
    for (int i = 0; i < 8; ++i)
#pragma unroll
        for (int j = 0; j < 4; ++j) acc[i][j] = (f32x4){0.f, 0.f, 0.f, 0.f};

    bf16x8 af00, af01, af10, af11;
    bf16x8 bf00, bf01, bf10, bf11, bf20, bf21, bf30, bf31;

    stageA(0, 0, 0); stageA(0, 0, 1);
    stageB(0, 0, 0); stageB(0, 0, 1);
    stageB(1, 1, 0); stageB(1, 1, 1);
    VMW4;
    BARR;

    const int niter = K >> 7;
    for (int i = 0; i < niter; ++i) {
        const bool nlast = (i + 1 < niter);
        const int kO  = 2 * i + 1;
        const int kN  = 2 * i + 2;
        const int kN1 = 2 * i + 3;
        PHASE(0, 0, stageA(1, kO, 0), ((void)0));
        PHASE(0, 1, stageA(1, kO, 1), ((void)0));
        PHASE(0, 2, if (nlast) stageB(0, kN, 0), ((void)0));
        PHASE(0, 3, if (nlast) stageB(0, kN, 1),
              if (nlast) { VMW4; } else { VMW0; });
        PHASE(1, 0, if (nlast) stageA(0, kN, 0), ((void)0));
        PHASE(1, 1, if (nlast) stageA(0, kN, 1), ((void)0));
        PHASE(1, 2, if (nlast) stageB(1, kN1, 0), ((void)0));
        PHASE(1, 3, if (nlast) stageB(1, kN1, 1),
              if (nlast) { VMW4; });
    }

    if (EPI == 0) {
        bf16_t* sC = (bf16_t*)smem;
#pragma unroll
        for (int n = 0; n < 4; ++n) {
            const int colL = wc * 64 + n * 16 + laneLow;
            const float bv = bias[bn * 256 + colL];
#pragma unroll
            for (int m = 0; m < 8; ++m) {
#pragma unroll
                for (int j = 0; j < 4; ++j) {
                    const int rowL = wr * 128 + m * 16 + (laneHi << 2) + j;
                    float v = acc[m][n][j] + bv;
                    int byte = (rowL << 9) + (colL << 1);
                    byte ^= ((rowL >> 2) & 3) << 5;
                    *(bf16_t*)((char*)sC + byte) = (bf16_t)gelu_f(v);
                }
            }
        }
        LGKM0;
        BARR;
        bf16_t* Cb = (bf16_t*)Cout;
        const size_t rb = PROBE ? 0 : (size_t)bm * 256;
        const size_t cb = PROBE ? 0 : (size_t)bn * 256;
        const size_t rowStride = PROBE ? 256 : (size_t)N;
#pragma unroll
        for (int s = 0; s < 16; ++s) {
            const int row = s * 16 + (tid >> 5);
            int byte = (row << 9) + ((tid & 31) << 4);
            byte ^= ((row >> 2) & 3) << 5;
            u32x4 v = *(const u32x4*)((char*)sC + byte);
            __builtin_nontemporal_store(
                v, (u32x4*)(&Cb[(rb + row) * rowStride + cb + ((tid & 31) << 3)]));
        }
    } else {
        const int r0 = bm * 256 + wr * 128 + (laneHi << 2);
        const int c0 = bn * 256 + wc * 64 + laneLow;
        float* Cf = (float*)Cout;
#pragma unroll
        for (int n = 0; n < 4; ++n) {
            const int col = c0 + n * 16;
            const float bv = bias[col];
#pragma unroll
            for (int m = 0; m < 8; ++m) {
#pragma unroll
                for (int j = 0; j < 4; ++j) {
                    const int row = r0 + m * 16 + j;
                    __builtin_nontemporal_store(acc[m][n][j] + bv,
                                                &Cf[(size_t)row * N + col]);
                }
            }
        }
    }
}

template <int EPI, int MAP>
__global__ __launch_bounds__(512, 2)
void gemm_kernel(const bf16_t* __restrict__ A, const bf16_t* __restrict__ Bt,
                 const float* __restrict__ bias, void* __restrict__ Cout,
                 int M, int N, int K) {
    __shared__ __align__(16) char smem[131072];
    gemm_body<EPI, MAP, 0>(A, Bt, bias, Cout, M, N, K, smem);
}

// PROBE: hot-staging control experiment (see header comment)
__global__ __launch_bounds__(512, 2)
void gemm_probe_hot(const bf16_t* __restrict__ A, const bf16_t* __restrict__ Bt,
                    const float* __restrict__ bias, void* __restrict__ Cout,
                    int M, int N, int K) {
    __shared__ __align__(16) char smem[131072];
    gemm_body<0, 1, 1>(A, Bt, bias, Cout, M, N, K, smem);
}

// ---------------------------------------------------------------------------
extern "C" void kernel_launch(void* const* d_in, const int* in_sizes, int n_in,
                              void* d_out, int out_size, void* d_ws, size_t ws_size,
                              hipStream_t stream) {
    const float* inputs = (const float*)d_in[0];
    const float* up_w   = (const float*)d_in[1];
    const float* up_b   = (const float*)d_in[2];
    const float* dn_w   = (const float*)d_in[3];
    const float* dn_b   = (const float*)d_in[4];
    float* out = (float*)d_out;

    const int D = in_sizes[4];            // 2048
    const int F = in_sizes[2];            // 8192
    const int M = in_sizes[0] / D;        // 8192 (B*S)

    size_t r0_bytes = (size_t)(M > F ? M : F) * D * 2;
    char* ws = (char*)d_ws;
    bf16_t* in_bf = (bf16_t*)ws;                                       // M x D
    bf16_t* wup_t = (bf16_t*)(ws + r0_bytes);                          // F x D
    bf16_t* mid   = (bf16_t*)(ws + r0_bytes + (size_t)F * D * 2);      // M x F
    bf16_t* wdn_t = (bf16_t*)(ws + r0_bytes + (size_t)F * D * 2 + (size_t)M * F * 2); // D x F

    // 1) fused prep: inputs -> bf16 + quantize up weights
    int ncvt = M * D;
    int cvtBlocks = ncvt / (8 * 256);
    int qupBlocks = ((D / 32) * F + 255) / 256;
    prep_kernel<<<cvtBlocks + qupBlocks, 256, 0, stream>>>(
        inputs, in_bf, ncvt, cvtBlocks, up_w, wup_t, D, F);

    // 2) GEMM1: mid = gelu(in @ W_up + b_up)
    gemm_kernel<0, 1><<<(M / 256) * (F / 256), 512, 0, stream>>>(
        in_bf, wup_t, up_b, (void*)mid, M, F, D);

    // 2b) PROBE (diagnostic): identical structure, kt pinned to 0 (L2-hot
    //     staging). Writes garbage to wdn_t scratch; quant_dn deterministically
    //     overwrites every byte right after.
    gemm_probe_hot<<<(M / 256) * (F / 256), 512, 0, stream>>>(
        in_bf, wup_t, up_b, (void*)wdn_t, M, F, D);

    // 3) quantize down weights (standalone again; XQ fusion regressed)
    int qdnBlocks = ((F / 32) * D + 255) / 256;
    quantize_kernel<<<qdnBlocks, 256, 0, stream>>>(dn_w, wdn_t, F, D);

    // 4) GEMM2: out = mid @ W_dn + b_dn
    gemm_kernel<1, 0><<<(M / 256) * (D / 256), 512, 0, stream>>>(
        mid, wdn_t, dn_b, (void*)out, M, D, F);
    (void)ws_size; (void)n_in; (void)out_size;
}

// Round 9
// 556.360 us; speedup vs baseline: 1.5170x; 1.5170x over previous
//
#include <hip/hip_runtime.h>
#include <hip/hip_bf16.h>

typedef __bf16 bf16_t;
typedef __attribute__((ext_vector_type(8))) __bf16 bf16x8;
typedef __attribute__((ext_vector_type(4))) float f32x4;
typedef __attribute__((ext_vector_type(4))) unsigned int u32x4;

// ---------------------------------------------------------------------------
__device__ __forceinline__ void gload_lds16(const bf16_t* g, bf16_t* l) {
    __builtin_amdgcn_global_load_lds(
        (const __attribute__((address_space(1))) void*)g,
        (__attribute__((address_space(3))) void*)l,
        16, 0, 0);
}

__device__ __forceinline__ float gelu_f(float v) {
    float u = 0.7978845608028654f * (v + 0.044715f * v * v * v);
    float e = __expf(-2.f * u);
    float t = __fdividef(1.f - e, 1.f + e);   // tanh(u)
    return 0.5f * v * (1.f + t);
}

// ---------------------------------------------------------------------------
// MXFP4 quantize: one (32-block b, column n) -> 32 dequantized bf16 written
// transposed. Exact: pow2 scale, E2M1 midpoint rounding, bf16-exact values.
__device__ __forceinline__ void quant_one(const float* __restrict__ w,
                                          bf16_t* __restrict__ wt,
                                          int K, int N, int tix) {
    int n = tix % N;
    int b = tix / N;
    const float* src = w + (size_t)b * 32 * N + n;
    float v[32];
    float amax = 0.f;
#pragma unroll
    for (int i = 0; i < 32; ++i) {
        v[i] = __builtin_nontemporal_load(src + (size_t)i * N);
        amax = fmaxf(amax, fabsf(v[i]));
    }
    unsigned eb = (__float_as_uint(amax) >> 23) & 0xFF;
    float scale = __uint_as_float((eb - 2u) << 23);        // 2^(E-2)
    float inv   = __uint_as_float((256u - eb) << 23);      // 2^-(E-2)
    if (amax == 0.f) { scale = 0.f; inv = 0.f; }
    bf16_t dq[32];
#pragma unroll
    for (int i = 0; i < 32; ++i) {
        float x  = v[i] * inv;
        float ax = fabsf(x);
        float q = ax < 0.25f ? 0.0f : ax < 0.75f ? 0.5f : ax < 1.25f ? 1.0f :
                  ax < 1.75f ? 1.5f : ax < 2.5f  ? 2.0f : ax < 3.5f  ? 3.0f :
                  ax < 5.0f  ? 4.0f : 6.0f;
        float d = copysignf(q * scale, x);
        dq[i] = (bf16_t)d;
    }
    bf16_t* dst = wt + (size_t)n * K + b * 32;
#pragma unroll
    for (int j = 0; j < 4; ++j) {
        bf16x8 p;
#pragma unroll
        for (int t = 0; t < 8; ++t) p[t] = dq[j * 8 + t];
        *(bf16x8*)(dst + j * 8) = p;
    }
}

// ---------------------------------------------------------------------------
// Fused prep: [0,cvtB): inputs->bf16; [cvtB,cvtB+qupB): quantize up-weights;
// [cvtB+qupB,...): quantize down-weights. All memory-bound, one launch.
__global__ void prep_kernel(const float* __restrict__ in, bf16_t* __restrict__ out,
                            int ncvt, int cvtB,
                            const float* __restrict__ upw, bf16_t* __restrict__ upwt,
                            int upK, int upN, int qupB,
                            const float* __restrict__ dnw, bf16_t* __restrict__ dnwt,
                            int dnK, int dnN) {
    int bid = blockIdx.x;
    if (bid < cvtB) {
        int i = (bid * blockDim.x + threadIdx.x) << 3;
        if (i >= ncvt) return;
        const f32x4* p = (const f32x4*)(in + i);
        f32x4 a = __builtin_nontemporal_load(p);
        f32x4 b = __builtin_nontemporal_load(p + 1);
        bf16x8 o;
        o[0] = (bf16_t)a[0]; o[1] = (bf16_t)a[1]; o[2] = (bf16_t)a[2]; o[3] = (bf16_t)a[3];
        o[4] = (bf16_t)b[0]; o[5] = (bf16_t)b[1]; o[6] = (bf16_t)b[2]; o[7] = (bf16_t)b[3];
        *(bf16x8*)(out + i) = o;
    } else if (bid < cvtB + qupB) {
        int tix = (bid - cvtB) * blockDim.x + threadIdx.x;
        if (tix >= (upK >> 5) * upN) return;
        quant_one(upw, upwt, upK, upN, tix);
    } else {
        int tix = (bid - cvtB - qupB) * blockDim.x + threadIdx.x;
        if (tix >= (dnK >> 5) * dnN) return;
        quant_one(dnw, dnwt, dnK, dnN, tix);
    }
}

// ---------------------------------------------------------------------------
// 8-phase 256x256xBK=64 bf16 GEMM machinery (T1+T2+T3+T4+T5).
#define VMW4  asm volatile("s_waitcnt vmcnt(4)" ::: "memory")
#define VMW0  asm volatile("s_waitcnt vmcnt(0)" ::: "memory")
#define BARR  asm volatile("s_barrier" ::: "memory")
#define LGKM0 asm volatile("s_waitcnt lgkmcnt(0)" ::: "memory")

#define MFMA_ROW(MI, A0, A1)                                                          \
    acc[MI][0] = __builtin_amdgcn_mfma_f32_16x16x32_bf16(A0, bf00, acc[MI][0],0,0,0); \
    acc[MI][0] = __builtin_amdgcn_mfma_f32_16x16x32_bf16(A1, bf01, acc[MI][0],0,0,0); \
    acc[MI][1] = __builtin_amdgcn_mfma_f32_16x16x32_bf16(A0, bf10, acc[MI][1],0,0,0); \
    acc[MI][1] = __builtin_amdgcn_mfma_f32_16x16x32_bf16(A1, bf11, acc[MI][1],0,0,0); \
    acc[MI][2] = __builtin_amdgcn_mfma_f32_16x16x32_bf16(A0, bf20, acc[MI][2],0,0,0); \
    acc[MI][2] = __builtin_amdgcn_mfma_f32_16x16x32_bf16(A1, bf21, acc[MI][2],0,0,0); \
    acc[MI][3] = __builtin_amdgcn_mfma_f32_16x16x32_bf16(A0, bf30, acc[MI][3],0,0,0); \
    acc[MI][3] = __builtin_amdgcn_mfma_f32_16x16x32_bf16(A1, bf31, acc[MI][3],0,0,0);

#define PHASE(BUF, P, STAGE_STMT, TAIL_STMT)                                          \
  {                                                                                   \
    af00 = lda(BUF, 2*(P),   0); af01 = lda(BUF, 2*(P),   1);                         \
    af10 = lda(BUF, 2*(P)+1, 0); af11 = lda(BUF, 2*(P)+1, 1);                         \
    if ((P) == 0) {                                                                   \
      bf00 = ldb(BUF,0,0); bf01 = ldb(BUF,0,1);                                       \
      bf10 = ldb(BUF,1,0); bf11 = ldb(BUF,1,1);                                       \
      bf20 = ldb(BUF,2,0); bf21 = ldb(BUF,2,1);                                       \
      bf30 = ldb(BUF,3,0); bf31 = ldb(BUF,3,1);                                       \
    }                                                                                 \
    STAGE_STMT;                                                                       \
    BARR;                                                                             \
    LGKM0;                                                                            \
    __builtin_amdgcn_s_setprio(1);                                                    \
    MFMA_ROW(2*(P),   af00, af01);                                                    \
    MFMA_ROW(2*(P)+1, af10, af11);                                                    \
    __builtin_amdgcn_s_setprio(0);                                                    \
    TAIL_STMT;                                                                        \
    BARR;                                                                             \
  }

// ---------------------------------------------------------------------------
// GEMM1 persistent-continuous: grid=256 (1 round). Block owns fixed bn; bm
// marches bm0+seg*8 over 4 segments. The K-pipeline is FLATTENED across
// segments: global tile t=0..127 (kt=t&31, bm=bm0+(t>>5)*8); counted vmcnt
// prefetch crosses segment boundaries (no drain, no per-segment prologue).
// Per-segment epilogue: direct NT bf16 stores (no LDS, no barrier) riding the
// live pipeline. Removes the per-round convoy (~50us/block) of 4-round grids.
__global__ __launch_bounds__(512, 2)
void gemm1_persistent(const bf16_t* __restrict__ A, const bf16_t* __restrict__ Bt,
                      const float* __restrict__ bias, bf16_t* __restrict__ C,
                      int M, int N, int K) {
    __shared__ __align__(16) char smem[131072];
    bf16_t* sAp = (bf16_t*)smem;               // [2][256*64]
    bf16_t* sBp = (bf16_t*)(smem + 65536);     // [2][256*64]
    const int tid     = threadIdx.x;
    const int lane    = tid & 63;
    const int wv      = tid >> 6;
    const int wr      = wv >> 2;
    const int wc      = wv & 3;
    const int laneLow = lane & 15;
    const int laneHi  = lane >> 4;

    // per-XCD window: 4 bm0-lanes x 8 bn (locality of round-3's MAP1)
    const int bid = blockIdx.x;
    const int xcd = bid & 7, q = bid >> 3;
    const int bn  = ((xcd & 3) << 3) + (q & 7);      // 0..31
    const int bm0 = ((xcd >> 2) << 2) + (q >> 3);    // 0..7

    const int sr8 = lane >> 3;
    const int swz = (((lane & 7) ^ sr8) << 3);
    const size_t aTh = (size_t)(wv * 8 + sr8) * K + swz;
    const bf16_t* bSrc = Bt + (size_t)(bn * 256 + wv * 8 + sr8) * K + swz;

    // stage by GLOBAL tile index t (0..127): seg = t>>5, kt = t&31
    auto stageA = [&](int b, int t, int h) {
        const bf16_t* s = A + (size_t)(bm0 + ((t >> 5) << 3)) * (size_t)(256 * K)
                            + aTh + (size_t)(h * 128) * K + (t & 31) * 64;
        gload_lds16(s,                &sAp[b * 16384 + (h * 128 + wv * 8) * 64]);
        gload_lds16(s + (size_t)64*K, &sAp[b * 16384 + (h * 128 + 64 + wv * 8) * 64]);
    };
    auto stageB = [&](int b, int t, int h) {
        const bf16_t* s = bSrc + (size_t)(h * 128) * K + (t & 31) * 64;
        gload_lds16(s,                &sBp[b * 16384 + (h * 128 + wv * 8) * 64]);
        gload_lds16(s + (size_t)64*K, &sBp[b * 16384 + (h * 128 + 64 + wv * 8) * 64]);
    };

    const int s7  = laneLow & 7;
    const int xk0 = ((laneHi) ^ s7) << 3;
    const int xk1 = ((4 + laneHi) ^ s7) << 3;
    const int aOffBase = (wr * 128 + laneLow) * 64;
    const int bOffBase = (wc * 64 + laneLow) * 64;
    auto lda = [&](int b, int m, int ks) -> bf16x8 {
        return *(const bf16x8*)(&sAp[b * 16384 + aOffBase + m * 1024 + (ks ? xk1 : xk0)]);
    };
    auto ldb = [&](int b, int n2, int ks) -> bf16x8 {
        return *(const bf16x8*)(&sBp[b * 16384 + bOffBase + n2 * 1024 + (ks ? xk1 : xk0)]);
    };

    f32x4 acc[8][4];
#pragma unroll
    for (int i = 0; i < 8; ++i)
#pragma unroll
        for (int j = 0; j < 4; ++j) acc[i][j] = (f32x4){0.f, 0.f, 0.f, 0.f};

    bf16x8 af00, af01, af10, af11;
    bf16x8 bf00, bf01, bf10, bf11, bf20, bf21, bf30, bf31;

    // prologue (once per kernel, not per segment)
    stageA(0, 0, 0); stageA(0, 0, 1);
    stageB(0, 0, 0); stageB(0, 0, 1);
    stageB(1, 1, 0); stageB(1, 1, 1);
    VMW4;
    BARR;

    const int c0 = bn * 256 + wc * 64 + laneLow;
#pragma unroll 1
    for (int g = 0; g < 64; ++g) {
        const bool nl = (g < 63);
        const int tA1 = 2 * g + 1, tN = 2 * g + 2, tN1 = 2 * g + 3;
        PHASE(0, 0, stageA(1, tA1, 0), ((void)0));
        PHASE(0, 1, stageA(1, tA1, 1), ((void)0));
        PHASE(0, 2, if (nl) stageB(0, tN, 0), ((void)0));
        PHASE(0, 3, if (nl) stageB(0, tN, 1),
              if (nl) { VMW4; } else { VMW0; });
        PHASE(1, 0, if (nl) stageA(0, tN, 0), ((void)0));
        PHASE(1, 1, if (nl) stageA(0, tN, 1), ((void)0));
        PHASE(1, 2, if (nl) stageB(1, tN1, 0), ((void)0));
        PHASE(1, 3, if (nl) stageB(1, tN1, 1),
              if (nl) { VMW4; });

        if ((g & 15) == 15) {
            // segment epilogue: direct NT bf16 stores; no LDS, no barrier --
            // the staged-ahead tiles for the next segment stay untouched.
            const int seg = g >> 4;
            const int r0 = (bm0 + (seg << 3)) * 256 + wr * 128 + (laneHi << 2);
#pragma unroll
            for (int n = 0; n < 4; ++n) {
                const int col = c0 + n * 16;
                const float bv = bias[col];
#pragma unroll
                for (int m = 0; m < 8; ++m) {
#pragma unroll
                    for (int j = 0; j < 4; ++j) {
                        const int row = r0 + m * 16 + j;
                        bf16_t h = (bf16_t)gelu_f(acc[m][n][j] + bv);
                        __builtin_nontemporal_store(
                            __builtin_bit_cast(short, h),
                            (short*)&C[(size_t)row * N + col]);
                    }
                    acc[m][n] = (f32x4){0.f, 0.f, 0.f, 0.f};
                }
            }
        }
    }
}

// ---------------------------------------------------------------------------
// GEMM2 (proven path, unchanged): 1 round, niter=64, EPI=f32 NT direct.
template <int EPI, int MAP>
__global__ __launch_bounds__(512, 2)
void gemm_kernel(const bf16_t* __restrict__ A, const bf16_t* __restrict__ Bt,
                 const float* __restrict__ bias, void* __restrict__ Cout,
                 int M, int N, int K) {
    __shared__ __align__(16) char smem[131072];
    bf16_t* sAp = (bf16_t*)smem;
    bf16_t* sBp = (bf16_t*)(smem + 65536);
    const int tid     = threadIdx.x;
    const int lane    = tid & 63;
    const int wv      = tid >> 6;
    const int wr      = wv >> 2;
    const int wc      = wv & 3;
    const int laneLow = lane & 15;
    const int laneHi  = lane >> 4;

    int bm, bn;
    const int bid = blockIdx.x;
    if (MAP == 1) {
        const int xcd = bid & 7;
        const int l   = bid >> 3;
        const int r   = l >> 5;
        const int u   = l & 31;
        bm = r * 8 + ((xcd >> 2) << 2) + (u >> 3);
        bn = ((xcd & 3) << 3) + (u & 7);
    } else {
        const int ntn = N >> 8;
        const int nwg = gridDim.x;
        int wg  = (bid & 7) * (nwg >> 3) + (bid >> 3);
        bm = wg / ntn; bn = wg % ntn;
    }

    const int sr8 = lane >> 3;
    const int swz = (((lane & 7) ^ sr8) << 3);
    const bf16_t* aSrc = A  + (size_t)(bm * 256 + wv * 8 + sr8) * K + swz;
    const bf16_t* bSrc = Bt + (size_t)(bn * 256 + wv * 8 + sr8) * K + swz;

    auto stageA = [&](int b, int kt, int h) {
        const bf16_t* s = aSrc + (size_t)(h * 128) * K + kt * 64;
        gload_lds16(s,                &sAp[b * 16384 + (h * 128 + wv * 8) * 64]);
        gload_lds16(s + (size_t)64*K, &sAp[b * 16384 + (h * 128 + 64 + wv * 8) * 64]);
    };
    auto stageB = [&](int b, int kt, int h) {
        const bf16_t* s = bSrc + (size_t)(h * 128) * K + kt * 64;
        gload_lds16(s,                &sBp[b * 16384 + (h * 128 + wv * 8) * 64]);
        gload_lds16(s + (size_t)64*K, &sBp[b * 16384 + (h * 128 + 64 + wv * 8) * 64]);
    };

    const int s7  = laneLow & 7;
    const int xk0 = ((laneHi) ^ s7) << 3;
    const int xk1 = ((4 + laneHi) ^ s7) << 3;
    const int aOffBase = (wr * 128 + laneLow) * 64;
    const int bOffBase = (wc * 64 + laneLow) * 64;
    auto lda = [&](int b, int m, int ks) -> bf16x8 {
        return *(const bf16x8*)(&sAp[b * 16384 + aOffBase + m * 1024 + (ks ? xk1 : xk0)]);
    };
    auto ldb = [&](int b, int n2, int ks) -> bf16x8 {
        return *(const bf16x8*)(&sBp[b * 16384 + bOffBase + n2 * 1024 + (ks ? xk1 : xk0)]);
    };

    f32x4 acc[8][4];
#pragma unroll
    for (int i = 0; i < 8; ++i)
#pragma unroll
        for (int j = 0; j < 4; ++j) acc[i][j] = (f32x4){0.f, 0.f, 0.f, 0.f};

    bf16x8 af00, af01, af10, af11;
    bf16x8 bf00, bf01, bf10, bf11, bf20, bf21, bf30, bf31;

    stageA(0, 0, 0); stageA(0, 0, 1);
    stageB(0, 0, 0); stageB(0, 0, 1);
    stageB(1, 1, 0); stageB(1, 1, 1);
    VMW4;
    BARR;

    const int niter = K >> 7;
    for (int i = 0; i < niter; ++i) {
        const bool nlast = (i + 1 < niter);
        const int kO  = 2 * i + 1;
        const int kN  = 2 * i + 2;
        const int kN1 = 2 * i + 3;
        PHASE(0, 0, stageA(1, kO, 0), ((void)0));
        PHASE(0, 1, stageA(1, kO, 1), ((void)0));
        PHASE(0, 2, if (nlast) stageB(0, kN, 0), ((void)0));
        PHASE(0, 3, if (nlast) stageB(0, kN, 1),
              if (nlast) { VMW4; } else { VMW0; });
        PHASE(1, 0, if (nlast) stageA(0, kN, 0), ((void)0));
        PHASE(1, 1, if (nlast) stageA(0, kN, 1), ((void)0));
        PHASE(1, 2, if (nlast) stageB(1, kN1, 0), ((void)0));
        PHASE(1, 3, if (nlast) stageB(1, kN1, 1),
              if (nlast) { VMW4; });
    }

    {
        const int r0 = bm * 256 + wr * 128 + (laneHi << 2);
        const int c0 = bn * 256 + wc * 64 + laneLow;
        float* Cf = (float*)Cout;
#pragma unroll
        for (int n = 0; n < 4; ++n) {
            const int col = c0 + n * 16;
            const float bv = bias[col];
#pragma unroll
            for (int m = 0; m < 8; ++m) {
#pragma unroll
                for (int j = 0; j < 4; ++j) {
                    const int row = r0 + m * 16 + j;
                    __builtin_nontemporal_store(acc[m][n][j] + bv,
                                                &Cf[(size_t)row * N + col]);
                }
            }
        }
    }
}

// ---------------------------------------------------------------------------
extern "C" void kernel_launch(void* const* d_in, const int* in_sizes, int n_in,
                              void* d_out, int out_size, void* d_ws, size_t ws_size,
                              hipStream_t stream) {
    const float* inputs = (const float*)d_in[0];
    const float* up_w   = (const float*)d_in[1];
    const float* up_b   = (const float*)d_in[2];
    const float* dn_w   = (const float*)d_in[3];
    const float* dn_b   = (const float*)d_in[4];
    float* out = (float*)d_out;

    const int D = in_sizes[4];            // 2048
    const int F = in_sizes[2];            // 8192
    const int M = in_sizes[0] / D;        // 8192 (B*S)

    size_t r0_bytes = (size_t)(M > F ? M : F) * D * 2;
    char* ws = (char*)d_ws;
    bf16_t* in_bf = (bf16_t*)ws;                                       // M x D
    bf16_t* wup_t = (bf16_t*)(ws + r0_bytes);                          // F x D
    bf16_t* mid   = (bf16_t*)(ws + r0_bytes + (size_t)F * D * 2);      // M x F
    bf16_t* wdn_t = (bf16_t*)(ws + r0_bytes + (size_t)F * D * 2 + (size_t)M * F * 2); // D x F

    // 1) fused prep: cvt + quantize-up + quantize-down (one launch)
    int ncvt = M * D;
    int cvtB = ncvt / (8 * 256);
    int qupB = ((D / 32) * F + 255) / 256;
    int qdnB = ((F / 32) * D + 255) / 256;
    prep_kernel<<<cvtB + qupB + qdnB, 256, 0, stream>>>(
        inputs, in_bf, ncvt, cvtB,
        up_w, wup_t, D, F, qupB,
        dn_w, wdn_t, F, D);

    // 2) GEMM1 persistent-continuous: mid = gelu(in @ W_up + b_up)
    gemm1_persistent<<<256, 512, 0, stream>>>(
        in_bf, wup_t, up_b, mid, M, F, D);

    // 3) GEMM2: out = mid @ W_dn + b_dn
    gemm_kernel<1, 0><<<(M / 256) * (D / 256), 512, 0, stream>>>(
        mid, wdn_t, dn_b, (void*)out, M, D, F);
    (void)ws_size; (void)n_in; (void)out_size;
}